// Round 6
// baseline (134.799 us; speedup 1.0000x reference)
//
#include <hip/hip_runtime.h>

#define HH   512
#define AA   128
#define SB   1024
#define BATCH 2

__device__ __forceinline__ float fast_rcp(float x) { return __builtin_amdgcn_rcpf(x); }
__device__ __forceinline__ float fast_ex2(float x) { return __builtin_amdgcn_exp2f(x); }

// Sum over a quad: v0/d0+v1/d1+v2/d2+v3/d3 = (na*p23 + nb*p01) / (p01*p23).
// 14 VALU + 1 rcp per 4 elements.
__device__ __forceinline__ void quad_acc(const float4 p, const float4 q4,
                                         const float4 vv, float& acc)
{
    const float d0 = fmaf(p.x, q4.x, 1.0f);
    const float d1 = fmaf(p.y, q4.y, 1.0f);
    const float d2 = fmaf(p.z, q4.z, 1.0f);
    const float d3 = fmaf(p.w, q4.w, 1.0f);
    const float p01 = d0 * d1, p23 = d2 * d3;
    const float na = fmaf(vv.x, d1, vv.y * d0);
    const float nb = fmaf(vv.z, d3, vv.w * d2);
    const float N  = fmaf(na, p23, nb * p01);
    acc = fmaf(N, fast_rcp(p01 * p23), acc);
}

// K1: partial GEMM C = lstm(2048x512) @ [w|u](512x256), K split 4 ways.
// NO LDS, k2a-style: lane = output column n (B loads coalesced, L2-resident,
// reg-double-buffered); A row-chunks block-uniform -> scalar s_load stream.
// 8 m-rows/thread. grid (256, 4) = 1024 blocks, 16 waves/CU.
// Block (0,0) zeroes rsum/colw/ctx (atomic targets of later kernels).
__global__ __launch_bounds__(256, 8) void k1_gemm(const float* __restrict__ lstm,
                                                  const float* __restrict__ w,
                                                  const float* __restrict__ u,
                                                  float* __restrict__ parts,
                                                  float* __restrict__ rsum,
                                                  float* __restrict__ colw,
                                                  float* __restrict__ ctx)
{
    const int t  = threadIdx.x;
    const int m0 = blockIdx.x * 8;                 // 256 m-chunks over 2048 rows
    const int kz = blockIdx.y * 128;               // 4 K-splits

    if (blockIdx.x == 0 && blockIdx.y == 0) {      // zero atomic targets
        #pragma unroll
        for (int r = 0; r < 8; ++r) { rsum[r * 256 + t] = 0.f; colw[r * 256 + t] = 0.f; }
        #pragma unroll
        for (int r = 0; r < 4; ++r) ctx[r * 256 + t] = 0.f;
    }

    const float* __restrict__ Bsrc = (t < 128) ? w : u;   // wave-uniform select
    const int nc = t & (AA - 1);

    float acc[8];
    #pragma unroll
    for (int m = 0; m < 8; ++m) acc[m] = 0.f;

    float bc[16], bn[16];
    #pragma unroll
    for (int kk = 0; kk < 16; ++kk)
        bc[kk] = Bsrc[(size_t)(kz + kk) * AA + nc];

    for (int kt = 0; kt < 8; ++kt) {               // 8 k-tiles of 16
        const int knext = (kt < 7) ? (kt + 1) * 16 : 0;   // last-iter dummy
        #pragma unroll
        for (int kk = 0; kk < 16; ++kk)
            bn[kk] = Bsrc[(size_t)(kz + knext + kk) * AA + nc];

        const float* __restrict__ Abase = &lstm[(size_t)m0 * HH + kz + kt * 16];
        #pragma unroll
        for (int m = 0; m < 8; ++m) {
            const float* __restrict__ Am = Abase + (size_t)m * HH;     // s_load
            const float4 a0 = *(const float4*)&Am[0];
            const float4 a1 = *(const float4*)&Am[4];
            const float4 a2 = *(const float4*)&Am[8];
            const float4 a3 = *(const float4*)&Am[12];
            float ac = acc[m];
            ac = fmaf(a0.x, bc[0],  ac); ac = fmaf(a0.y, bc[1],  ac);
            ac = fmaf(a0.z, bc[2],  ac); ac = fmaf(a0.w, bc[3],  ac);
            ac = fmaf(a1.x, bc[4],  ac); ac = fmaf(a1.y, bc[5],  ac);
            ac = fmaf(a1.z, bc[6],  ac); ac = fmaf(a1.w, bc[7],  ac);
            ac = fmaf(a2.x, bc[8],  ac); ac = fmaf(a2.y, bc[9],  ac);
            ac = fmaf(a2.z, bc[10], ac); ac = fmaf(a2.w, bc[11], ac);
            ac = fmaf(a3.x, bc[12], ac); ac = fmaf(a3.y, bc[13], ac);
            ac = fmaf(a3.z, bc[14], ac); ac = fmaf(a3.w, bc[15], ac);
            acc[m] = ac;
        }
        #pragma unroll
        for (int kk = 0; kk < 16; ++kk) bc[kk] = bn[kk];
    }

    float* __restrict__ part = parts + (size_t)blockIdx.y * (2048 * 256);
    #pragma unroll
    for (int m = 0; m < 8; ++m)
        part[(size_t)(m0 + m) * 256 + t] = acc[m];   // coalesced dword stores
}

// K1b: [P|Q] = exp2(KK * sum of 4 partials). grid (512), 256 threads, float4/thread.
__global__ __launch_bounds__(256) void k1b_combine_exp(const float* __restrict__ parts,
                                                       float* __restrict__ P,
                                                       float* __restrict__ Q)
{
    const float KK = 2.8853900817779268f;            // 2 * log2(e)
    const int idx = blockIdx.x * 256 + threadIdx.x;  // 0..131071 float4s
    const float4 c0 = ((const float4*)parts)[idx];
    const float4 c1 = ((const float4*)parts)[idx + 131072];
    const float4 c2 = ((const float4*)parts)[idx + 262144];
    const float4 c3 = ((const float4*)parts)[idx + 393216];
    float4 o;
    o.x = fast_ex2(KK * ((c0.x + c1.x) + (c2.x + c3.x)));
    o.y = fast_ex2(KK * ((c0.y + c1.y) + (c2.y + c3.y)));
    o.z = fast_ex2(KK * ((c0.z + c1.z) + (c2.z + c3.z)));
    o.w = fast_ex2(KK * ((c0.w + c1.w) + (c2.w + c3.w)));
    const int m  = idx >> 6;                          // row 0..2047
    const int qd = idx & 63;                          // float4 within 256-col row
    float* dst = (qd < 32) ? &P[(size_t)m * AA + qd * 4]
                           : &Q[(size_t)m * AA + (qd - 32) * 4];
    *(float4*)dst = o;
}

// K2a: E[b,i,j] = exp(e) into attn region + row sums via atomics.
// Thread owns one j (Q chunk-prefetched in regs); P rows + v on scalar pipe.
// 4 i-rows/block -> 8192 waves = 8 waves/SIMD. grid (4, 256, 2) = 2048 blocks.
__global__ __launch_bounds__(256, 8) void k2a_escore(const float* __restrict__ P,
                                                     const float* __restrict__ Q,
                                                     const float* __restrict__ v,
                                                     float* __restrict__ E,
                                                     float* __restrict__ rsum)
{
    const int b  = blockIdx.z;
    const int i0 = blockIdx.y * 4;
    const int j  = blockIdx.x * 256 + threadIdx.x;

    const float4* __restrict__ Qr = (const float4*)&Q[((size_t)b * SB + j) * AA];
    const float*  __restrict__ Pb = &P[((size_t)b * SB + i0) * AA];

    float acc[4];
    #pragma unroll
    for (int i = 0; i < 4; ++i) acc[i] = 0.f;
    float Vacc = 0.f;

    float4 qc[4], qn[4];
    #pragma unroll
    for (int x2 = 0; x2 < 4; ++x2) qc[x2] = Qr[x2];

    for (int xc = 0; xc < 8; ++xc) {
        const int nb4 = (xc < 7) ? (xc + 1) * 4 : 0;   // last-iter dummy
        #pragma unroll
        for (int x2 = 0; x2 < 4; ++x2) qn[x2] = Qr[nb4 + x2];
        #pragma unroll
        for (int x2 = 0; x2 < 4; ++x2) {
            const float4 q4 = qc[x2];
            const float4 vv = *(const float4*)&v[(xc * 4 + x2) * 4];    // s_load
            Vacc += (vv.x + vv.y) + (vv.z + vv.w);
            #pragma unroll
            for (int i = 0; i < 4; ++i) {
                const float4 p = *(const float4*)&Pb[(size_t)i * AA + (xc * 4 + x2) * 4]; // s_load
                quad_acc(p, q4, vv, acc[i]);
            }
        }
        #pragma unroll
        for (int x2 = 0; x2 < 4; ++x2) qc[x2] = qn[x2];
    }

    // e = Vacc - 2*acc; E = exp2(L2E*Vacc - 2*L2E*acc). |e| <= ~9 -> no max pass.
    const float L2E  = 1.4426950408889634f;
    const float base = Vacc * L2E;
    float* __restrict__ Eout = &E[((size_t)(b * SB + i0)) * SB + j];
    const int lane = threadIdx.x & 63;
    #pragma unroll
    for (int i = 0; i < 4; ++i) {
        const float e = fast_ex2(fmaf(acc[i], -2.0f * L2E, base));
        Eout[(size_t)i * SB] = e;
        float s = e;
        #pragma unroll
        for (int off = 32; off > 0; off >>= 1) s += __shfl_xor(s, off);
        if (lane == 0) atomicAdd(&rsum[b * SB + i0 + i], s);
    }
}

// K2b: attn = E / rsum[row] in place + colw column-sum via atomics.
// grid (4, 128, 2) = 1024 blocks, 256 threads; 8 rows x 256 j each.
__global__ __launch_bounds__(256) void k2b_scale_colsum(float* __restrict__ attn,
                                                        const float* __restrict__ rsum,
                                                        float* __restrict__ colw)
{
    const int b  = blockIdx.z;
    const int i0 = blockIdx.y * 8;
    const int j  = blockIdx.x * 256 + threadIdx.x;

    float csum = 0.f;
    #pragma unroll
    for (int i = 0; i < 8; ++i) {
        const int row = b * SB + i0 + i;
        const float inv = fast_rcp(rsum[row]);            // s_load + rcp
        float* __restrict__ ap = &attn[(size_t)row * SB + j];
        const float a = (*ap) * inv;
        *ap = a;
        csum += a;
    }
    atomicAdd(&colw[b * SB + j], csum);
}

// K4: ctx[b,h] = sum_j colw[b,j] * lstm[b,j,h]. grid (2, 8, 2), 256 threads.
__global__ __launch_bounds__(256) void k4_context(const float* __restrict__ lstm,
                                                  const float* __restrict__ colw,
                                                  float* __restrict__ ctx)
{
    const int b  = blockIdx.z;
    const int h  = blockIdx.x * 256 + threadIdx.x;
    const int j0 = blockIdx.y * 128;
    __shared__ float cw[128];
    if (threadIdx.x < 128) cw[threadIdx.x] = colw[b * SB + j0 + threadIdx.x];
    __syncthreads();
    float acc = 0.f;
    #pragma unroll 8
    for (int jj = 0; jj < 128; ++jj)
        acc = fmaf(cw[jj], lstm[(size_t)(b * SB + j0 + jj) * HH + h], acc);
    atomicAdd(&ctx[b * HH + h], acc);
}

extern "C" void kernel_launch(void* const* d_in, const int* in_sizes, int n_in,
                              void* d_out, int out_size, void* d_ws, size_t ws_size,
                              hipStream_t stream)
{
    const float* lstm = (const float*)d_in[0];   // (B,S,H)
    const float* w    = (const float*)d_in[1];   // (H,A)
    const float* u    = (const float*)d_in[2];   // (H,A)
    const float* v    = (const float*)d_in[3];   // (A,)

    float* out  = (float*)d_out;
    float* ctx  = out;                     // (B,H)   = 1024 floats
    float* attn = out + BATCH * HH;        // (B,S,S) = 2M floats

    float* parts = (float*)d_ws;                          // 4 x 2048*256 floats = 8 MB
    float* P     = parts + (size_t)4 * 2048 * 256;        // 1 MB
    float* Qb    = P     + (size_t)BATCH * SB * AA;       // 1 MB
    float* rsum  = Qb    + (size_t)BATCH * SB * AA;       // 8 KB
    float* colw  = rsum  + (size_t)BATCH * SB;            // 8 KB

    k1_gemm<<<dim3(256, 4), 256, 0, stream>>>(lstm, w, u, parts, rsum, colw, ctx);
    k1b_combine_exp<<<dim3(512), 256, 0, stream>>>(parts, P, Qb);
    k2a_escore<<<dim3(4, 256, BATCH), 256, 0, stream>>>(P, Qb, v, attn, rsum);
    k2b_scale_colsum<<<dim3(4, 128, BATCH), 256, 0, stream>>>(attn, rsum, colw);
    k4_context<<<dim3(2, 8, BATCH), 256, 0, stream>>>(lstm, colw, ctx);
}

// Round 7
// 101.944 us; speedup vs baseline: 1.3223x; 1.3223x over previous
//
#include <hip/hip_runtime.h>

#define HH   512
#define AA   128
#define SB   1024
#define BATCH 2

__device__ __forceinline__ float fast_rcp(float x) { return __builtin_amdgcn_rcpf(x); }
__device__ __forceinline__ float fast_ex2(float x) { return __builtin_amdgcn_exp2f(x); }

// Sum over a quad: v0/d0+v1/d1+v2/d2+v3/d3 = (na*p23 + nb*p01) / (p01*p23).
// 13 VALU + 1 rcp per 4 elements.
__device__ __forceinline__ void quad_acc(const float4 p, const float4 q4,
                                         const float4 vv, float& acc)
{
    const float d0 = fmaf(p.x, q4.x, 1.0f);
    const float d1 = fmaf(p.y, q4.y, 1.0f);
    const float d2 = fmaf(p.z, q4.z, 1.0f);
    const float d3 = fmaf(p.w, q4.w, 1.0f);
    const float p01 = d0 * d1, p23 = d2 * d3;
    const float na = fmaf(vv.x, d1, vv.y * d0);
    const float nb = fmaf(vv.z, d3, vv.w * d2);
    const float N  = fmaf(na, p23, nb * p01);
    acc = fmaf(N, fast_rcp(p01 * p23), acc);
}

// Process one 16-element chunk (4 quads) against 4 P-rows. c is compile-time.
__device__ __forceinline__ void proc_chunk(const float* __restrict__ Pb,
                                           const float* __restrict__ v,
                                           const int c,
                                           const float4 q0, const float4 q1,
                                           const float4 q2, const float4 q3,
                                           float* __restrict__ acc)
{
    #pragma unroll
    for (int x2 = 0; x2 < 4; ++x2) {
        const float4 q4 = (x2 == 0) ? q0 : (x2 == 1) ? q1 : (x2 == 2) ? q2 : q3;
        const int off = (c * 4 + x2) * 4;
        const float4 vv = *(const float4*)&v[off];               // s_load (uniform)
        #pragma unroll
        for (int i = 0; i < 4; ++i)
            quad_acc(*(const float4*)&Pb[i * AA + off], q4, vv, acc[i]);  // s_load
    }
}

// K1: partial GEMM C = lstm(2048x512) @ [w|u](512x256), K split 4 ways.
// NO LDS: lane = output column (B coalesced, L2-resident, ping-pong reg-buffered);
// A row-chunks block-uniform -> scalar s_load stream. 8 m-rows/thread.
// grid (256, 4) = 1024 blocks. Block (0,0) zeroes atomic targets + computes vsum.
__global__ __launch_bounds__(256) void k1_gemm(const float* __restrict__ lstm,
                                               const float* __restrict__ w,
                                               const float* __restrict__ u,
                                               const float* __restrict__ v,
                                               float* __restrict__ parts,
                                               float* __restrict__ rsum,
                                               float* __restrict__ colw,
                                               float* __restrict__ ctx,
                                               float* __restrict__ vsum)
{
    const int t  = threadIdx.x;
    const int m0 = blockIdx.x * 8;
    const int kz = blockIdx.y * 128;

    if (blockIdx.x == 0 && blockIdx.y == 0) {
        #pragma unroll
        for (int r = 0; r < 8; ++r) { rsum[r * 256 + t] = 0.f; colw[r * 256 + t] = 0.f; }
        #pragma unroll
        for (int r = 0; r < 4; ++r) ctx[r * 256 + t] = 0.f;
        if (t < 64) {
            float s = v[t] + v[t + 64];
            #pragma unroll
            for (int off = 32; off > 0; off >>= 1) s += __shfl_xor(s, off);
            if (t == 0) vsum[0] = s;
        }
    }

    const float* __restrict__ Bsrc = (t < 128) ? w : u;   // wave-uniform select
    const int nc = t & (AA - 1);

    float acc[8];
    #pragma unroll
    for (int m = 0; m < 8; ++m) acc[m] = 0.f;

    float ba[16], bb[16];
    #pragma unroll
    for (int kk = 0; kk < 16; ++kk)
        ba[kk] = Bsrc[(size_t)(kz + kk) * AA + nc];

    #define K1_TILE(KT, BREG)                                                  \
        do {                                                                   \
            const float* __restrict__ Ab = &lstm[(size_t)m0 * HH + kz + (KT) * 16]; \
            _Pragma("unroll")                                                  \
            for (int m = 0; m < 8; ++m) {                                      \
                const float* __restrict__ Am = Ab + (size_t)m * HH;            \
                const float4 a0 = *(const float4*)&Am[0];                      \
                const float4 a1 = *(const float4*)&Am[4];                      \
                const float4 a2 = *(const float4*)&Am[8];                      \
                const float4 a3 = *(const float4*)&Am[12];                     \
                float ac = acc[m];                                             \
                ac = fmaf(a0.x, BREG[0],  ac); ac = fmaf(a0.y, BREG[1],  ac);  \
                ac = fmaf(a0.z, BREG[2],  ac); ac = fmaf(a0.w, BREG[3],  ac);  \
                ac = fmaf(a1.x, BREG[4],  ac); ac = fmaf(a1.y, BREG[5],  ac);  \
                ac = fmaf(a1.z, BREG[6],  ac); ac = fmaf(a1.w, BREG[7],  ac);  \
                ac = fmaf(a2.x, BREG[8],  ac); ac = fmaf(a2.y, BREG[9],  ac);  \
                ac = fmaf(a2.z, BREG[10], ac); ac = fmaf(a2.w, BREG[11], ac);  \
                ac = fmaf(a3.x, BREG[12], ac); ac = fmaf(a3.y, BREG[13], ac);  \
                ac = fmaf(a3.z, BREG[14], ac); ac = fmaf(a3.w, BREG[15], ac);  \
                acc[m] = ac;                                                   \
            }                                                                  \
        } while (0)

    #pragma unroll
    for (int kt = 0; kt < 8; kt += 2) {
        #pragma unroll
        for (int kk = 0; kk < 16; ++kk)
            bb[kk] = Bsrc[(size_t)(kz + (kt + 1) * 16 + kk) * AA + nc];
        K1_TILE(kt, ba);
        if (kt + 2 < 8) {
            #pragma unroll
            for (int kk = 0; kk < 16; ++kk)
                ba[kk] = Bsrc[(size_t)(kz + (kt + 2) * 16 + kk) * AA + nc];
        }
        K1_TILE(kt + 1, bb);
    }
    #undef K1_TILE

    float* __restrict__ part = parts + (size_t)blockIdx.y * (2048 * 256);
    #pragma unroll
    for (int m = 0; m < 8; ++m)
        part[(size_t)(m0 + m) * 256 + t] = acc[m];   // coalesced stores
}

// K1b: [P|Q] = exp2(KK * sum of 4 partials). grid (512), 256 threads, float4/thread.
__global__ __launch_bounds__(256) void k1b_combine_exp(const float* __restrict__ parts,
                                                       float* __restrict__ P,
                                                       float* __restrict__ Q)
{
    const float KK = 2.8853900817779268f;            // 2 * log2(e)
    const int idx = blockIdx.x * 256 + threadIdx.x;  // 0..131071 float4s
    const float4 c0 = ((const float4*)parts)[idx];
    const float4 c1 = ((const float4*)parts)[idx + 131072];
    const float4 c2 = ((const float4*)parts)[idx + 262144];
    const float4 c3 = ((const float4*)parts)[idx + 393216];
    float4 o;
    o.x = fast_ex2(KK * ((c0.x + c1.x) + (c2.x + c3.x)));
    o.y = fast_ex2(KK * ((c0.y + c1.y) + (c2.y + c3.y)));
    o.z = fast_ex2(KK * ((c0.z + c1.z) + (c2.z + c3.z)));
    o.w = fast_ex2(KK * ((c0.w + c1.w) + (c2.w + c3.w)));
    const int m  = idx >> 6;                          // row 0..2047
    const int qd = idx & 63;                          // float4 within 256-col row
    float* dst = (qd < 32) ? &P[(size_t)m * AA + qd * 4]
                           : &Q[(size_t)m * AA + (qd - 32) * 4];
    *(float4*)dst = o;
}

// K2a: E[b,i,j] = exp(e) into attn region + row sums via atomics.
// Thread owns one j; Q ping-pong reg-buffered (no rotation copies); P + v on
// the scalar pipe. 4 i-rows/block -> 8192 waves = 8/SIMD (natural VGPR ~56,
// NO forced launch bounds: round-6's (256,8) caused scratch spills).
// grid (4, 256, 2) = 2048 blocks.
__global__ __launch_bounds__(256) void k2a_escore(const float* __restrict__ P,
                                                  const float* __restrict__ Q,
                                                  const float* __restrict__ v,
                                                  const float* __restrict__ vsum,
                                                  float* __restrict__ E,
                                                  float* __restrict__ rsum)
{
    const int b  = blockIdx.z;
    const int i0 = blockIdx.y * 4;
    const int j  = blockIdx.x * 256 + threadIdx.x;

    const float4* __restrict__ Qr = (const float4*)&Q[((size_t)b * SB + j) * AA];
    const float*  __restrict__ Pb = &P[((size_t)b * SB + i0) * AA];

    float acc[4] = {0.f, 0.f, 0.f, 0.f};

    float4 qa0 = Qr[0], qa1 = Qr[1], qa2 = Qr[2], qa3 = Qr[3];
    float4 qb0, qb1, qb2, qb3;

    #pragma unroll
    for (int xc = 0; xc < 8; xc += 2) {
        qb0 = Qr[(xc + 1) * 4 + 0]; qb1 = Qr[(xc + 1) * 4 + 1];
        qb2 = Qr[(xc + 1) * 4 + 2]; qb3 = Qr[(xc + 1) * 4 + 3];
        proc_chunk(Pb, v, xc, qa0, qa1, qa2, qa3, acc);
        if (xc + 2 < 8) {
            qa0 = Qr[(xc + 2) * 4 + 0]; qa1 = Qr[(xc + 2) * 4 + 1];
            qa2 = Qr[(xc + 2) * 4 + 2]; qa3 = Qr[(xc + 2) * 4 + 3];
        }
        proc_chunk(Pb, v, xc + 1, qb0, qb1, qb2, qb3, acc);
    }

    // e = Vsum - 2*acc; E = exp2(L2E*Vsum - 2*L2E*acc). |e| <= ~9 -> no max pass.
    const float L2E  = 1.4426950408889634f;
    const float base = vsum[0] * L2E;                 // s_load (uniform)
    float* __restrict__ Eout = &E[((size_t)(b * SB + i0)) * SB + j];
    const int lane = threadIdx.x & 63;
    #pragma unroll
    for (int i = 0; i < 4; ++i) {
        const float e = fast_ex2(fmaf(acc[i], -2.0f * L2E, base));
        Eout[(size_t)i * SB] = e;
        float s = e;
        #pragma unroll
        for (int off = 32; off > 0; off >>= 1) s += __shfl_xor(s, off);
        if (lane == 0) atomicAdd(&rsum[b * SB + i0 + i], s);
    }
}

// K2b: attn = E / rsum[row] in place + colw column-sum via atomics.
// grid (4, 128, 2) = 1024 blocks, 256 threads; 8 rows x 256 j each.
__global__ __launch_bounds__(256) void k2b_scale_colsum(float* __restrict__ attn,
                                                        const float* __restrict__ rsum,
                                                        float* __restrict__ colw)
{
    const int b  = blockIdx.z;
    const int i0 = blockIdx.y * 8;
    const int j  = blockIdx.x * 256 + threadIdx.x;

    float csum = 0.f;
    #pragma unroll
    for (int i = 0; i < 8; ++i) {
        const int row = b * SB + i0 + i;
        const float inv = fast_rcp(rsum[row]);            // s_load + rcp
        float* __restrict__ ap = &attn[(size_t)row * SB + j];
        const float a = (*ap) * inv;
        *ap = a;
        csum += a;
    }
    atomicAdd(&colw[b * SB + j], csum);
}

// K4: ctx[b,h] = sum_j colw[b,j] * lstm[b,j,h]. grid (2, 8, 2), 256 threads.
__global__ __launch_bounds__(256) void k4_context(const float* __restrict__ lstm,
                                                  const float* __restrict__ colw,
                                                  float* __restrict__ ctx)
{
    const int b  = blockIdx.z;
    const int h  = blockIdx.x * 256 + threadIdx.x;
    const int j0 = blockIdx.y * 128;
    __shared__ float cw[128];
    if (threadIdx.x < 128) cw[threadIdx.x] = colw[b * SB + j0 + threadIdx.x];
    __syncthreads();
    float acc = 0.f;
    #pragma unroll 8
    for (int jj = 0; jj < 128; ++jj)
        acc = fmaf(cw[jj], lstm[(size_t)(b * SB + j0 + jj) * HH + h], acc);
    atomicAdd(&ctx[b * HH + h], acc);
}

extern "C" void kernel_launch(void* const* d_in, const int* in_sizes, int n_in,
                              void* d_out, int out_size, void* d_ws, size_t ws_size,
                              hipStream_t stream)
{
    const float* lstm = (const float*)d_in[0];   // (B,S,H)
    const float* w    = (const float*)d_in[1];   // (H,A)
    const float* u    = (const float*)d_in[2];   // (H,A)
    const float* v    = (const float*)d_in[3];   // (A,)

    float* out  = (float*)d_out;
    float* ctx  = out;                     // (B,H)   = 1024 floats
    float* attn = out + BATCH * HH;        // (B,S,S) = 2M floats

    float* parts = (float*)d_ws;                          // 4 x 2048*256 floats = 8 MB
    float* P     = parts + (size_t)4 * 2048 * 256;        // 1 MB
    float* Qb    = P     + (size_t)BATCH * SB * AA;       // 1 MB
    float* rsum  = Qb    + (size_t)BATCH * SB * AA;       // 8 KB
    float* colw  = rsum  + (size_t)BATCH * SB;            // 8 KB
    float* vsum  = colw  + (size_t)BATCH * SB;            // 4 B

    k1_gemm<<<dim3(256, 4), 256, 0, stream>>>(lstm, w, u, v, parts, rsum, colw, ctx, vsum);
    k1b_combine_exp<<<dim3(512), 256, 0, stream>>>(parts, P, Qb);
    k2a_escore<<<dim3(4, 256, BATCH), 256, 0, stream>>>(P, Qb, v, vsum, attn, rsum);
    k2b_scale_colsum<<<dim3(4, 128, BATCH), 256, 0, stream>>>(attn, rsum, colw);
    k4_context<<<dim3(2, 8, BATCH), 256, 0, stream>>>(lstm, colw, ctx);
}

// Round 8
// 82.998 us; speedup vs baseline: 1.6241x; 1.2283x over previous
//
#include <hip/hip_runtime.h>

#define HH   512
#define AA   128
#define SB   1024
#define BATCH 2

__device__ __forceinline__ float fast_rcp(float x) { return __builtin_amdgcn_rcpf(x); }
__device__ __forceinline__ float fast_ex2(float x) { return __builtin_amdgcn_exp2f(x); }

// Sum over a quad: v0/d0+v1/d1+v2/d2+v3/d3 = (na*p23 + nb*p01) / (p01*p23).
// 11 VALU + 1 rcp per 4 elements.
__device__ __forceinline__ void quad_acc(const float4 p, const float4 q4,
                                         const float4 vv, float& acc)
{
    const float d0 = fmaf(p.x, q4.x, 1.0f);
    const float d1 = fmaf(p.y, q4.y, 1.0f);
    const float d2 = fmaf(p.z, q4.z, 1.0f);
    const float d3 = fmaf(p.w, q4.w, 1.0f);
    const float p01 = d0 * d1, p23 = d2 * d3;
    const float na = fmaf(vv.x, d1, vv.y * d0);
    const float nb = fmaf(vv.z, d3, vv.w * d2);
    const float N  = fmaf(na, p23, nb * p01);
    acc = fmaf(N, fast_rcp(p01 * p23), acc);
}

// K1: partial GEMM C = lstm(2048x512) @ [w|u](512x256), K split 4 ways.
// Lean-register / high-wave: 4 m-rows/thread, grid (512, 4) = 2048 blocks
// (8 waves/SIMD). lane = output column (B coalesced dword loads, L2-resident);
// A row-chunks block-uniform -> scalar s_load stream. NO LDS, NO ping-pong.
// Block (0,0) zeroes atomic targets + computes vsum.
__global__ __launch_bounds__(256) void k1_gemm(const float* __restrict__ lstm,
                                               const float* __restrict__ w,
                                               const float* __restrict__ u,
                                               const float* __restrict__ v,
                                               float* __restrict__ parts,
                                               float* __restrict__ rsum,
                                               float* __restrict__ colw,
                                               float* __restrict__ ctx,
                                               float* __restrict__ vsum)
{
    const int t  = threadIdx.x;
    const int m0 = blockIdx.x * 4;                 // 512 m-chunks over 2048 rows
    const int kz = blockIdx.y * 128;               // 4 K-splits

    if (blockIdx.x == 0 && blockIdx.y == 0) {      // zero atomic targets
        #pragma unroll
        for (int r = 0; r < 8; ++r) { rsum[r * 256 + t] = 0.f; colw[r * 256 + t] = 0.f; }
        #pragma unroll
        for (int r = 0; r < 4; ++r) ctx[r * 256 + t] = 0.f;
        if (t < 64) {
            float s = v[t] + v[t + 64];
            #pragma unroll
            for (int off = 32; off > 0; off >>= 1) s += __shfl_xor(s, off);
            if (t == 0) vsum[0] = s;
        }
    }

    const float* __restrict__ Bsrc = (t < 128) ? w : u;   // wave-uniform select
    const int nc = t & (AA - 1);

    float acc[4] = {0.f, 0.f, 0.f, 0.f};

    #pragma unroll 1
    for (int kt = 0; kt < 8; ++kt) {               // 8 k-tiles of 16
        const int k0 = kz + kt * 16;
        float bq[16];
        #pragma unroll
        for (int kk = 0; kk < 16; ++kk)
            bq[kk] = Bsrc[(size_t)(k0 + kk) * AA + nc];    // 16 indep coalesced loads

        const float* __restrict__ Ab = &lstm[(size_t)m0 * HH + k0];
        #pragma unroll
        for (int m = 0; m < 4; ++m) {
            const float* __restrict__ Am = Ab + (size_t)m * HH;   // s_load stream
            const float4 a0 = *(const float4*)&Am[0];
            const float4 a1 = *(const float4*)&Am[4];
            const float4 a2 = *(const float4*)&Am[8];
            const float4 a3 = *(const float4*)&Am[12];
            float ac = acc[m];
            ac = fmaf(a0.x, bq[0],  ac); ac = fmaf(a0.y, bq[1],  ac);
            ac = fmaf(a0.z, bq[2],  ac); ac = fmaf(a0.w, bq[3],  ac);
            ac = fmaf(a1.x, bq[4],  ac); ac = fmaf(a1.y, bq[5],  ac);
            ac = fmaf(a1.z, bq[6],  ac); ac = fmaf(a1.w, bq[7],  ac);
            ac = fmaf(a2.x, bq[8],  ac); ac = fmaf(a2.y, bq[9],  ac);
            ac = fmaf(a2.z, bq[10], ac); ac = fmaf(a2.w, bq[11], ac);
            ac = fmaf(a3.x, bq[12], ac); ac = fmaf(a3.y, bq[13], ac);
            ac = fmaf(a3.z, bq[14], ac); ac = fmaf(a3.w, bq[15], ac);
            acc[m] = ac;
        }
    }

    float* __restrict__ part = parts + (size_t)blockIdx.y * (2048 * 256);
    #pragma unroll
    for (int m = 0; m < 4; ++m)
        part[(size_t)(m0 + m) * 256 + t] = acc[m];   // coalesced stores
}

// K1b: [P|Q] = exp2(KK * sum of 4 partials). grid (512), 256 threads, float4/thread.
__global__ __launch_bounds__(256) void k1b_combine_exp(const float* __restrict__ parts,
                                                       float* __restrict__ P,
                                                       float* __restrict__ Q)
{
    const float KK = 2.8853900817779268f;            // 2 * log2(e)
    const int idx = blockIdx.x * 256 + threadIdx.x;  // 0..131071 float4s
    const float4 c0 = ((const float4*)parts)[idx];
    const float4 c1 = ((const float4*)parts)[idx + 131072];
    const float4 c2 = ((const float4*)parts)[idx + 262144];
    const float4 c3 = ((const float4*)parts)[idx + 393216];
    float4 o;
    o.x = fast_ex2(KK * ((c0.x + c1.x) + (c2.x + c3.x)));
    o.y = fast_ex2(KK * ((c0.y + c1.y) + (c2.y + c3.y)));
    o.z = fast_ex2(KK * ((c0.z + c1.z) + (c2.z + c3.z)));
    o.w = fast_ex2(KK * ((c0.w + c1.w) + (c2.w + c3.w)));
    const int m  = idx >> 6;                          // row 0..2047
    const int qd = idx & 63;                          // float4 within 256-col row
    float* dst = (qd < 32) ? &P[(size_t)m * AA + qd * 4]
                           : &Q[(size_t)m * AA + (qd - 32) * 4];
    *(float4*)dst = o;
}

// K2a: E[b,i,j] = exp(e) into attn region + row sums via atomics.
// Lean-register / high-wave: 4 i-rows/thread, grid (4, 256, 2) = 2048 blocks
// (8192 waves = 8/SIMD). Thread owns one j; Q chunk = 4 float4 loaded at loop
// top under unroll-1 (no ping-pong — waves hide the latency). P + v + vsum on
// the scalar pipe. Target VGPR < 64 (round-7's 84-VGPR unroll hit the cliff).
__global__ __launch_bounds__(256) void k2a_escore(const float* __restrict__ P,
                                                  const float* __restrict__ Q,
                                                  const float* __restrict__ v,
                                                  const float* __restrict__ vsum,
                                                  float* __restrict__ E,
                                                  float* __restrict__ rsum)
{
    const int b  = blockIdx.z;
    const int i0 = blockIdx.y * 4;
    const int j  = blockIdx.x * 256 + threadIdx.x;

    const float4* __restrict__ Qr = (const float4*)&Q[((size_t)b * SB + j) * AA];
    const float*  __restrict__ Pb = &P[((size_t)b * SB + i0) * AA];

    float acc[4] = {0.f, 0.f, 0.f, 0.f};

    #pragma unroll 1
    for (int xc = 0; xc < 8; ++xc) {
        const float4 q0 = Qr[xc * 4 + 0];
        const float4 q1 = Qr[xc * 4 + 1];
        const float4 q2 = Qr[xc * 4 + 2];
        const float4 q3 = Qr[xc * 4 + 3];
        #pragma unroll
        for (int x2 = 0; x2 < 4; ++x2) {
            const float4 q4 = (x2 == 0) ? q0 : (x2 == 1) ? q1 : (x2 == 2) ? q2 : q3;
            const int off = (xc * 4 + x2) * 4;
            const float4 vv = *(const float4*)&v[off];            // s_load (uniform)
            #pragma unroll
            for (int i = 0; i < 4; ++i)
                quad_acc(*(const float4*)&Pb[i * AA + off], q4, vv, acc[i]); // s_load
        }
    }

    // e = Vsum - 2*acc; E = exp2(L2E*Vsum - 2*L2E*acc). |e| <= ~9 -> no max pass.
    const float L2E  = 1.4426950408889634f;
    const float base = vsum[0] * L2E;                 // s_load (uniform)
    float* __restrict__ Eout = &E[((size_t)(b * SB + i0)) * SB + j];
    const int lane = threadIdx.x & 63;
    #pragma unroll
    for (int i = 0; i < 4; ++i) {
        const float e = fast_ex2(fmaf(acc[i], -2.0f * L2E, base));
        Eout[(size_t)i * SB] = e;
        float s = e;
        #pragma unroll
        for (int off = 32; off > 0; off >>= 1) s += __shfl_xor(s, off);
        if (lane == 0) atomicAdd(&rsum[b * SB + i0 + i], s);
    }
}

// K2b: attn = E / rsum[row] in place + colw column-sum via atomics.
// grid (4, 128, 2) = 1024 blocks, 256 threads; 8 rows x 256 j each.
__global__ __launch_bounds__(256) void k2b_scale_colsum(float* __restrict__ attn,
                                                        const float* __restrict__ rsum,
                                                        float* __restrict__ colw)
{
    const int b  = blockIdx.z;
    const int i0 = blockIdx.y * 8;
    const int j  = blockIdx.x * 256 + threadIdx.x;

    float csum = 0.f;
    #pragma unroll
    for (int i = 0; i < 8; ++i) {
        const int row = b * SB + i0 + i;
        const float inv = fast_rcp(rsum[row]);            // s_load + rcp
        float* __restrict__ ap = &attn[(size_t)row * SB + j];
        const float a = (*ap) * inv;
        *ap = a;
        csum += a;
    }
    atomicAdd(&colw[b * SB + j], csum);
}

// K4: ctx[b,h] = sum_j colw[b,j] * lstm[b,j,h]. grid (2, 8, 2), 256 threads.
__global__ __launch_bounds__(256) void k4_context(const float* __restrict__ lstm,
                                                  const float* __restrict__ colw,
                                                  float* __restrict__ ctx)
{
    const int b  = blockIdx.z;
    const int h  = blockIdx.x * 256 + threadIdx.x;
    const int j0 = blockIdx.y * 128;
    __shared__ float cw[128];
    if (threadIdx.x < 128) cw[threadIdx.x] = colw[b * SB + j0 + threadIdx.x];
    __syncthreads();
    float acc = 0.f;
    #pragma unroll 8
    for (int jj = 0; jj < 128; ++jj)
        acc = fmaf(cw[jj], lstm[(size_t)(b * SB + j0 + jj) * HH + h], acc);
    atomicAdd(&ctx[b * HH + h], acc);
}

extern "C" void kernel_launch(void* const* d_in, const int* in_sizes, int n_in,
                              void* d_out, int out_size, void* d_ws, size_t ws_size,
                              hipStream_t stream)
{
    const float* lstm = (const float*)d_in[0];   // (B,S,H)
    const float* w    = (const float*)d_in[1];   // (H,A)
    const float* u    = (const float*)d_in[2];   // (H,A)
    const float* v    = (const float*)d_in[3];   // (A,)

    float* out  = (float*)d_out;
    float* ctx  = out;                     // (B,H)   = 1024 floats
    float* attn = out + BATCH * HH;        // (B,S,S) = 2M floats

    float* parts = (float*)d_ws;                          // 4 x 2048*256 floats = 8 MB
    float* P     = parts + (size_t)4 * 2048 * 256;        // 1 MB
    float* Qb    = P     + (size_t)BATCH * SB * AA;       // 1 MB
    float* rsum  = Qb    + (size_t)BATCH * SB * AA;       // 8 KB
    float* colw  = rsum  + (size_t)BATCH * SB;            // 8 KB
    float* vsum  = colw  + (size_t)BATCH * SB;            // 4 B

    k1_gemm<<<dim3(512, 4), 256, 0, stream>>>(lstm, w, u, v, parts, rsum, colw, ctx, vsum);
    k1b_combine_exp<<<dim3(512), 256, 0, stream>>>(parts, P, Qb);
    k2a_escore<<<dim3(4, 256, BATCH), 256, 0, stream>>>(P, Qb, v, vsum, attn, rsum);
    k2b_scale_colsum<<<dim3(4, 128, BATCH), 256, 0, stream>>>(attn, rsum, colw);
    k4_context<<<dim3(2, 8, BATCH), 256, 0, stream>>>(lstm, colw, ctx);
}

// Round 9
// 80.268 us; speedup vs baseline: 1.6794x; 1.0340x over previous
//
#include <hip/hip_runtime.h>

#define HH   512
#define AA   128
#define SB   1024
#define BATCH 2

__device__ __forceinline__ float fast_rcp(float x) { return __builtin_amdgcn_rcpf(x); }
__device__ __forceinline__ float fast_ex2(float x) { return __builtin_amdgcn_exp2f(x); }

// Sum over a quad: v0/d0+v1/d1+v2/d2+v3/d3 = (na*p23 + nb*p01) / (p01*p23).
// 11 VALU + 1 rcp per 4 elements; all operands in VGPRs (no constant-bus).
__device__ __forceinline__ void quad_acc(const float4 p, const float4 q4,
                                         const float4 vv, float& acc)
{
    const float d0 = fmaf(p.x, q4.x, 1.0f);
    const float d1 = fmaf(p.y, q4.y, 1.0f);
    const float d2 = fmaf(p.z, q4.z, 1.0f);
    const float d3 = fmaf(p.w, q4.w, 1.0f);
    const float p01 = d0 * d1, p23 = d2 * d3;
    const float na = fmaf(vv.x, d1, vv.y * d0);
    const float nb = fmaf(vv.z, d3, vv.w * d2);
    const float N  = fmaf(na, p23, nb * p01);
    acc = fmaf(N, fast_rcp(p01 * p23), acc);
}

// K1: partial GEMM C = lstm(2048x512) @ [w|u](512x256), K split in 2 halves.
// Round-3 proven structure: BM=64, BN=32, BK=32, 256 threads, 4m x 2n/thread,
// LDS tiles (broadcast / 2-way patterns). grid (32, 8, 2).
// Block (0,0,z) zeroes atomic targets; (0,0,0) computes vsum.
__global__ __launch_bounds__(256) void k1_gemm(const float* __restrict__ lstm,
                                               const float* __restrict__ w,
                                               const float* __restrict__ u,
                                               const float* __restrict__ v,
                                               float* __restrict__ part0,
                                               float* __restrict__ part1,
                                               float* __restrict__ rsum,
                                               float* __restrict__ colw,
                                               float* __restrict__ ctx,
                                               float* __restrict__ vsum)
{
    __shared__ float As[32][68];   // [k][m]
    __shared__ float Bs[32][36];   // [k][n]
    const int t  = threadIdx.x;
    const int bx = blockIdx.x, by = blockIdx.y, bz = blockIdx.z;
    const int m0 = bx * 64;
    const int n0 = by * 32;                        // global col 0..255
    const float* __restrict__ Bsrc = (n0 < AA) ? w : u;
    const int ncol = n0 & (AA - 1);

    if (bx == 0 && by == 0) {                      // zero atomic targets (split by bz)
        #pragma unroll
        for (int r = 0; r < 4; ++r) {
            rsum[bz * 1024 + r * 256 + t] = 0.f;
            colw[bz * 1024 + r * 256 + t] = 0.f;
        }
        ctx[bz * 512 + t]       = 0.f;
        ctx[bz * 512 + 256 + t] = 0.f;
        if (bz == 0 && t < 64) {
            float s = v[t] + v[t + 64];
            #pragma unroll
            for (int off = 32; off > 0; off >>= 1) s += __shfl_xor(s, off);
            if (t == 0) vsum[0] = s;
        }
    }

    const int r  = t & 63;                         // A staging row
    const int kq = (t >> 6) * 8;                   // wave-uniform k-quad pair
    const int kk = t >> 3;                         // B staging k
    const int nq = (t & 7) * 4;                    // B staging n-quad
    const int tm = t >> 4;                         // 0..15 -> rows 4tm..4tm+3
    const int tn = t & 15;                         // 0..15 -> cols 2tn..2tn+1

    float acc[4][2];
    #pragma unroll
    for (int i = 0; i < 4; ++i) { acc[i][0] = 0.f; acc[i][1] = 0.f; }

    for (int kc = 0; kc < 8; ++kc) {
        const int k0 = bz * 256 + kc * 32;
        const float* ap = &lstm[(size_t)(m0 + r) * HH + k0 + kq];
        const float4 a0 = *(const float4*)&ap[0];
        const float4 a1 = *(const float4*)&ap[4];
        As[kq + 0][r] = a0.x; As[kq + 1][r] = a0.y;
        As[kq + 2][r] = a0.z; As[kq + 3][r] = a0.w;
        As[kq + 4][r] = a1.x; As[kq + 5][r] = a1.y;
        As[kq + 6][r] = a1.z; As[kq + 7][r] = a1.w;
        const float4 bv = *(const float4*)&Bsrc[(size_t)(k0 + kk) * AA + ncol + nq];
        *(float4*)&Bs[kk][nq] = bv;
        __syncthreads();
        #pragma unroll
        for (int k = 0; k < 32; ++k) {
            const float4 av = *(const float4*)&As[k][4 * tm];
            const float2 bb = *(const float2*)&Bs[k][2 * tn];
            acc[0][0] = fmaf(av.x, bb.x, acc[0][0]);
            acc[0][1] = fmaf(av.x, bb.y, acc[0][1]);
            acc[1][0] = fmaf(av.y, bb.x, acc[1][0]);
            acc[1][1] = fmaf(av.y, bb.y, acc[1][1]);
            acc[2][0] = fmaf(av.z, bb.x, acc[2][0]);
            acc[2][1] = fmaf(av.z, bb.y, acc[2][1]);
            acc[3][0] = fmaf(av.w, bb.x, acc[3][0]);
            acc[3][1] = fmaf(av.w, bb.y, acc[3][1]);
        }
        __syncthreads();
    }

    float* __restrict__ part = bz ? part1 : part0;
    #pragma unroll
    for (int mi = 0; mi < 4; ++mi) {
        float2 st; st.x = acc[mi][0]; st.y = acc[mi][1];
        *(float2*)&part[(size_t)(m0 + 4 * tm + mi) * 256 + n0 + 2 * tn] = st;
    }
}

// K1b: [P|Q] = exp2(KK * (part0 + part1)). grid (512), 256 threads, float4/thread.
__global__ __launch_bounds__(256) void k1b_combine_exp(const float* __restrict__ part0,
                                                       const float* __restrict__ part1,
                                                       float* __restrict__ P,
                                                       float* __restrict__ Q)
{
    const float KK = 2.8853900817779268f;            // 2 * log2(e)
    const int idx = blockIdx.x * 256 + threadIdx.x;  // 0..131071 float4s
    const float4 c0 = ((const float4*)part0)[idx];
    const float4 c1 = ((const float4*)part1)[idx];
    float4 o;
    o.x = fast_ex2(KK * (c0.x + c1.x));
    o.y = fast_ex2(KK * (c0.y + c1.y));
    o.z = fast_ex2(KK * (c0.z + c1.z));
    o.w = fast_ex2(KK * (c0.w + c1.w));
    const int m  = idx >> 6;                          // row 0..2047
    const int qd = idx & 63;                          // float4 within 256-col row
    float* dst = (qd < 32) ? &P[(size_t)m * AA + qd * 4]
                           : &Q[(size_t)m * AA + (qd - 32) * 4];
    *(float4*)dst = o;
}

// K2a: E[b,i,j] = exp(e) into attn region + row sums via atomics.
// LDS-broadcast P (round-1's proven structure, leaner): 4 i-rows staged in LDS
// (2KB) + v (512B); thread owns J=2 j-columns so each P ds_read feeds 8
// outputs (halves LDS-pipe load). Q xc-chunks in regs (~70 VGPR; only 4
// waves/SIMD needed). grid (2, 256, 2) = 1024 blocks, 256 threads.
__global__ __launch_bounds__(256) void k2a_escore(const float* __restrict__ P,
                                                  const float* __restrict__ Q,
                                                  const float* __restrict__ v,
                                                  const float* __restrict__ vsum,
                                                  float* __restrict__ E,
                                                  float* __restrict__ rsum)
{
    __shared__ float Pl[4 * AA];
    __shared__ float vl[AA];
    const int b  = blockIdx.z;
    const int i0 = blockIdx.y * 4;
    const int jb = blockIdx.x * 512;
    const int t  = threadIdx.x;

    if (t < 128)      ((float4*)Pl)[t] = ((const float4*)&P[((size_t)b * SB + i0) * AA])[t];
    else if (t < 160) ((float4*)vl)[t - 128] = ((const float4*)v)[t - 128];
    __syncthreads();

    const int j0 = jb + t;
    const float4* __restrict__ Qr0 = (const float4*)&Q[((size_t)b * SB + j0) * AA];
    const float4* __restrict__ Qr1 = (const float4*)&Q[((size_t)b * SB + j0 + 256) * AA];

    float acc[4][2];
    #pragma unroll
    for (int i = 0; i < 4; ++i) { acc[i][0] = 0.f; acc[i][1] = 0.f; }

    #pragma unroll 1
    for (int xc = 0; xc < 8; ++xc) {
        float4 qa0 = Qr0[xc * 4 + 0], qa1 = Qr0[xc * 4 + 1];
        float4 qa2 = Qr0[xc * 4 + 2], qa3 = Qr0[xc * 4 + 3];
        float4 qb0 = Qr1[xc * 4 + 0], qb1 = Qr1[xc * 4 + 1];
        float4 qb2 = Qr1[xc * 4 + 2], qb3 = Qr1[xc * 4 + 3];
        #pragma unroll
        for (int x2 = 0; x2 < 4; ++x2) {
            const float4 qa = (x2 == 0) ? qa0 : (x2 == 1) ? qa1 : (x2 == 2) ? qa2 : qa3;
            const float4 qb = (x2 == 0) ? qb0 : (x2 == 1) ? qb1 : (x2 == 2) ? qb2 : qb3;
            const int off = (xc * 4 + x2) * 4;
            const float4 vv = *(const float4*)&vl[off];          // LDS broadcast
            #pragma unroll
            for (int i = 0; i < 4; ++i) {
                const float4 p = *(const float4*)&Pl[i * AA + off];  // LDS broadcast
                quad_acc(p, qa, vv, acc[i][0]);
                quad_acc(p, qb, vv, acc[i][1]);
            }
        }
    }

    // e = Vsum - 2*acc; E = exp2(L2E*Vsum - 2*L2E*acc). |e| <= ~9 -> no max pass.
    const float L2E  = 1.4426950408889634f;
    const float base = vsum[0] * L2E;                 // one uniform s_load
    float* __restrict__ Eout = &E[((size_t)(b * SB + i0)) * SB + j0];
    const int lane = t & 63;
    #pragma unroll
    for (int i = 0; i < 4; ++i) {
        const float e0 = fast_ex2(fmaf(acc[i][0], -2.0f * L2E, base));
        const float e1 = fast_ex2(fmaf(acc[i][1], -2.0f * L2E, base));
        Eout[(size_t)i * SB]       = e0;
        Eout[(size_t)i * SB + 256] = e1;
        float s = e0 + e1;
        #pragma unroll
        for (int off = 32; off > 0; off >>= 1) s += __shfl_xor(s, off);
        if (lane == 0) atomicAdd(&rsum[b * SB + i0 + i], s);
    }
}

// K2b: attn = E / rsum[row] in place + colw column-sum via atomics.
// grid (4, 128, 2) = 1024 blocks, 256 threads; 8 rows x 256 j each.
__global__ __launch_bounds__(256) void k2b_scale_colsum(float* __restrict__ attn,
                                                        const float* __restrict__ rsum,
                                                        float* __restrict__ colw)
{
    const int b  = blockIdx.z;
    const int i0 = blockIdx.y * 8;
    const int j  = blockIdx.x * 256 + threadIdx.x;

    float csum = 0.f;
    #pragma unroll
    for (int i = 0; i < 8; ++i) {
        const int row = b * SB + i0 + i;
        const float inv = fast_rcp(rsum[row]);            // s_load + rcp
        float* __restrict__ ap = &attn[(size_t)row * SB + j];
        const float a = (*ap) * inv;
        *ap = a;
        csum += a;
    }
    atomicAdd(&colw[b * SB + j], csum);
}

// K4: ctx[b,h] = sum_j colw[b,j] * lstm[b,j,h]. grid (2, 8, 2), 256 threads.
__global__ __launch_bounds__(256) void k4_context(const float* __restrict__ lstm,
                                                  const float* __restrict__ colw,
                                                  float* __restrict__ ctx)
{
    const int b  = blockIdx.z;
    const int h  = blockIdx.x * 256 + threadIdx.x;
    const int j0 = blockIdx.y * 128;
    __shared__ float cw[128];
    if (threadIdx.x < 128) cw[threadIdx.x] = colw[b * SB + j0 + threadIdx.x];
    __syncthreads();
    float acc = 0.f;
    #pragma unroll 8
    for (int jj = 0; jj < 128; ++jj)
        acc = fmaf(cw[jj], lstm[(size_t)(b * SB + j0 + jj) * HH + h], acc);
    atomicAdd(&ctx[b * HH + h], acc);
}

extern "C" void kernel_launch(void* const* d_in, const int* in_sizes, int n_in,
                              void* d_out, int out_size, void* d_ws, size_t ws_size,
                              hipStream_t stream)
{
    const float* lstm = (const float*)d_in[0];   // (B,S,H)
    const float* w    = (const float*)d_in[1];   // (H,A)
    const float* u    = (const float*)d_in[2];   // (H,A)
    const float* v    = (const float*)d_in[3];   // (A,)

    float* out  = (float*)d_out;
    float* ctx  = out;                     // (B,H)   = 1024 floats
    float* attn = out + BATCH * HH;        // (B,S,S) = 2M floats

    float* part0 = (float*)d_ws;                          // 2048*256 = 2 MB
    float* part1 = part0 + (size_t)2048 * 256;            // 2 MB
    float* P     = part1 + (size_t)2048 * 256;            // 1 MB
    float* Qb    = P     + (size_t)BATCH * SB * AA;       // 1 MB
    float* rsum  = Qb    + (size_t)BATCH * SB * AA;       // 8 KB
    float* colw  = rsum  + (size_t)BATCH * SB;            // 8 KB
    float* vsum  = colw  + (size_t)BATCH * SB;            // 4 B

    k1_gemm<<<dim3(32, 8, 2), 256, 0, stream>>>(lstm, w, u, v, part0, part1,
                                                rsum, colw, ctx, vsum);
    k1b_combine_exp<<<dim3(512), 256, 0, stream>>>(part0, part1, P, Qb);
    k2a_escore<<<dim3(2, 256, BATCH), 256, 0, stream>>>(P, Qb, v, vsum, attn, rsum);
    k2b_scale_colsum<<<dim3(4, 128, BATCH), 256, 0, stream>>>(attn, rsum, colw);
    k4_context<<<dim3(2, 8, BATCH), 256, 0, stream>>>(lstm, colw, ctx);
}

// Round 10
// 75.877 us; speedup vs baseline: 1.7765x; 1.0579x over previous
//
#include <hip/hip_runtime.h>

#define HH   512
#define AA   128
#define SB   1024
#define BATCH 2

__device__ __forceinline__ float fast_rcp(float x) { return __builtin_amdgcn_rcpf(x); }
__device__ __forceinline__ float fast_ex2(float x) { return __builtin_amdgcn_exp2f(x); }

// Sum over a quad: v0/d0+v1/d1+v2/d2+v3/d3 = (na*p23 + nb*p01) / (p01*p23).
// 11 VALU + 1 rcp per 4 elements; all operands in VGPRs.
__device__ __forceinline__ void quad_acc(const float4 p, const float4 q4,
                                         const float4 vv, float& acc)
{
    const float d0 = fmaf(p.x, q4.x, 1.0f);
    const float d1 = fmaf(p.y, q4.y, 1.0f);
    const float d2 = fmaf(p.z, q4.z, 1.0f);
    const float d3 = fmaf(p.w, q4.w, 1.0f);
    const float p01 = d0 * d1, p23 = d2 * d3;
    const float na = fmaf(vv.x, d1, vv.y * d0);
    const float nb = fmaf(vv.z, d3, vv.w * d2);
    const float N  = fmaf(na, p23, nb * p01);
    acc = fmaf(N, fast_rcp(p01 * p23), acc);
}

// K1: partial GEMM C = lstm(2048x512) @ [w|u](512x256), K split in 2 halves.
// Round-3 proven LDS structure: BM=64, BN=32, BK=32, 4m x 2n/thread. grid (32,8,2).
// Block (0,0,z) zeroes ctx; (0,0,0) computes vsum.
__global__ __launch_bounds__(256) void k1_gemm(const float* __restrict__ lstm,
                                               const float* __restrict__ w,
                                               const float* __restrict__ u,
                                               const float* __restrict__ v,
                                               float* __restrict__ part0,
                                               float* __restrict__ part1,
                                               float* __restrict__ ctx,
                                               float* __restrict__ vsum)
{
    __shared__ float As[32][68];   // [k][m]
    __shared__ float Bs[32][36];   // [k][n]
    const int t  = threadIdx.x;
    const int bx = blockIdx.x, by = blockIdx.y, bz = blockIdx.z;
    const int m0 = bx * 64;
    const int n0 = by * 32;                        // global col 0..255
    const float* __restrict__ Bsrc = (n0 < AA) ? w : u;
    const int ncol = n0 & (AA - 1);

    if (bx == 0 && by == 0) {                      // zero ctx (k4 atomic target)
        ctx[bz * 512 + t]       = 0.f;
        ctx[bz * 512 + 256 + t] = 0.f;
        if (bz == 0 && t < 64) {
            float s = v[t] + v[t + 64];
            #pragma unroll
            for (int off = 32; off > 0; off >>= 1) s += __shfl_xor(s, off);
            if (t == 0) vsum[0] = s;
        }
    }

    const int r  = t & 63;                         // A staging row
    const int kq = (t >> 6) * 8;                   // wave-uniform k-quad pair
    const int kk = t >> 3;                         // B staging k
    const int nq = (t & 7) * 4;                    // B staging n-quad
    const int tm = t >> 4;                         // rows 4tm..4tm+3
    const int tn = t & 15;                         // cols 2tn..2tn+1

    float acc[4][2];
    #pragma unroll
    for (int i = 0; i < 4; ++i) { acc[i][0] = 0.f; acc[i][1] = 0.f; }

    for (int kc = 0; kc < 8; ++kc) {
        const int k0 = bz * 256 + kc * 32;
        const float* ap = &lstm[(size_t)(m0 + r) * HH + k0 + kq];
        const float4 a0 = *(const float4*)&ap[0];
        const float4 a1 = *(const float4*)&ap[4];
        As[kq + 0][r] = a0.x; As[kq + 1][r] = a0.y;
        As[kq + 2][r] = a0.z; As[kq + 3][r] = a0.w;
        As[kq + 4][r] = a1.x; As[kq + 5][r] = a1.y;
        As[kq + 6][r] = a1.z; As[kq + 7][r] = a1.w;
        const float4 bv = *(const float4*)&Bsrc[(size_t)(k0 + kk) * AA + ncol + nq];
        *(float4*)&Bs[kk][nq] = bv;
        __syncthreads();
        #pragma unroll
        for (int k = 0; k < 32; ++k) {
            const float4 av = *(const float4*)&As[k][4 * tm];
            const float2 bb = *(const float2*)&Bs[k][2 * tn];
            acc[0][0] = fmaf(av.x, bb.x, acc[0][0]);
            acc[0][1] = fmaf(av.x, bb.y, acc[0][1]);
            acc[1][0] = fmaf(av.y, bb.x, acc[1][0]);
            acc[1][1] = fmaf(av.y, bb.y, acc[1][1]);
            acc[2][0] = fmaf(av.z, bb.x, acc[2][0]);
            acc[2][1] = fmaf(av.z, bb.y, acc[2][1]);
            acc[3][0] = fmaf(av.w, bb.x, acc[3][0]);
            acc[3][1] = fmaf(av.w, bb.y, acc[3][1]);
        }
        __syncthreads();
    }

    float* __restrict__ part = bz ? part1 : part0;
    #pragma unroll
    for (int mi = 0; mi < 4; ++mi) {
        float2 st; st.x = acc[mi][0]; st.y = acc[mi][1];
        *(float2*)&part[(size_t)(m0 + 4 * tm + mi) * 256 + n0 + 2 * tn] = st;
    }
}

// K1b: o = exp2(KK*(part0+part1)); P row-major [m][a]; Q TILED: Qt[b][aq][j]
// (float4 = a-quad of column j) so k2a's Q loads are lane-coalesced.
// grid (512), 256 threads, one float4/thread.
__global__ __launch_bounds__(256) void k1b_combine_exp(const float* __restrict__ part0,
                                                       const float* __restrict__ part1,
                                                       float* __restrict__ P,
                                                       float* __restrict__ Qt)
{
    const float KK = 2.8853900817779268f;            // 2 * log2(e)
    const int idx = blockIdx.x * 256 + threadIdx.x;  // 0..131071 float4s
    const float4 c0 = ((const float4*)part0)[idx];
    const float4 c1 = ((const float4*)part1)[idx];
    float4 o;
    o.x = fast_ex2(KK * (c0.x + c1.x));
    o.y = fast_ex2(KK * (c0.y + c1.y));
    o.z = fast_ex2(KK * (c0.z + c1.z));
    o.w = fast_ex2(KK * (c0.w + c1.w));
    const int m  = idx >> 6;                          // global row 0..2047
    const int qd = idx & 63;                          // a-quad within 256-col row
    if (qd < 32) {
        *(float4*)&P[(size_t)m * AA + qd * 4] = o;
    } else {
        const int aq = qd - 32;                       // 0..31
        const int b  = m >> 10;
        const int j  = m & (SB - 1);
        ((float4*)Qt)[((size_t)(b * 32 + aq)) * SB + j] = o;
    }
}

// K2a: fused e-score + softmax + column partials.
// Block = 2 i-rows x all 1024 j (256 threads, J=4: j = t + 256k). grid (512, 2).
// P rows + v in LDS (broadcast b128); Q from tiled Qt -> coalesced b128 loads.
// E kept in regs, row-sums block-reduced, attn written ONCE normalized,
// per-block column partials to ws (non-atomic).
__global__ __launch_bounds__(256) void k2a_fused(const float* __restrict__ P,
                                                 const float* __restrict__ Qt,
                                                 const float* __restrict__ v,
                                                 const float* __restrict__ vsum,
                                                 float* __restrict__ attn,
                                                 float* __restrict__ colw_part)
{
    __shared__ float Pl[2 * AA];
    __shared__ float vl[AA];
    __shared__ float red[2][4];
    const int b  = blockIdx.y;
    const int i0 = blockIdx.x * 2;
    const int t  = threadIdx.x;

    if (t < 64)      ((float4*)Pl)[t] = ((const float4*)&P[((size_t)b * SB + i0) * AA])[t];
    else if (t < 96) ((float4*)vl)[t - 64] = ((const float4*)v)[t - 64];
    __syncthreads();

    const float4* __restrict__ Qb4 = (const float4*)Qt + (size_t)b * 32 * SB;

    float acc[2][4];
    #pragma unroll
    for (int i = 0; i < 2; ++i)
        #pragma unroll
        for (int k = 0; k < 4; ++k) acc[i][k] = 0.f;

    #pragma unroll 2
    for (int aq = 0; aq < 32; ++aq) {
        const float4* __restrict__ qs = Qb4 + (size_t)aq * SB + t;
        const float4 q0 = qs[0];
        const float4 q1 = qs[256];
        const float4 q2 = qs[512];
        const float4 q3 = qs[768];
        const float4 vv = *(const float4*)&vl[aq * 4];           // LDS broadcast
        const float4 p0 = *(const float4*)&Pl[aq * 4];           // LDS broadcast
        const float4 p1 = *(const float4*)&Pl[AA + aq * 4];
        quad_acc(p0, q0, vv, acc[0][0]);
        quad_acc(p0, q1, vv, acc[0][1]);
        quad_acc(p0, q2, vv, acc[0][2]);
        quad_acc(p0, q3, vv, acc[0][3]);
        quad_acc(p1, q0, vv, acc[1][0]);
        quad_acc(p1, q1, vv, acc[1][1]);
        quad_acc(p1, q2, vv, acc[1][2]);
        quad_acc(p1, q3, vv, acc[1][3]);
    }

    // e = Vsum - 2*acc; E = exp2(L2E*Vsum - 2*L2E*acc). |e| <= ~9 -> no max pass.
    const float L2E  = 1.4426950408889634f;
    const float base = vsum[0] * L2E;                 // one uniform s_load
    float E[2][4];
    #pragma unroll
    for (int i = 0; i < 2; ++i)
        #pragma unroll
        for (int k = 0; k < 4; ++k)
            E[i][k] = fast_ex2(fmaf(acc[i][k], -2.0f * L2E, base));

    const int lane = t & 63, wv = t >> 6;
    #pragma unroll
    for (int i = 0; i < 2; ++i) {
        float s = (E[i][0] + E[i][1]) + (E[i][2] + E[i][3]);
        #pragma unroll
        for (int off = 32; off > 0; off >>= 1) s += __shfl_xor(s, off);
        if (lane == 0) red[i][wv] = s;
    }
    __syncthreads();

    const float inv0 = fast_rcp((red[0][0] + red[0][1]) + (red[0][2] + red[0][3]));
    const float inv1 = fast_rcp((red[1][0] + red[1][1]) + (red[1][2] + red[1][3]));

    float* __restrict__ arow = &attn[((size_t)(b * SB + i0)) * SB];
    float* __restrict__ cp   = &colw_part[((size_t)b * 512 + blockIdx.x) * SB];
    #pragma unroll
    for (int k = 0; k < 4; ++k) {
        const float a0 = E[0][k] * inv0;
        const float a1 = E[1][k] * inv1;
        arow[t + 256 * k]      = a0;
        arow[SB + t + 256 * k] = a1;
        cp[t + 256 * k] = a0 + a1;
    }
}

// K4: reduce 512 column partials -> cw, then ctx[b,h] += sum_j cw[j]*lstm[b,j,h].
// grid (2 hc, 8 jc, 2 b) = 32 blocks, 256 threads.
__global__ __launch_bounds__(256) void k4_context(const float* __restrict__ lstm,
                                                  const float* __restrict__ colw_part,
                                                  float* __restrict__ ctx)
{
    const int b  = blockIdx.z;
    const int j0 = blockIdx.y * 128;
    const int h  = blockIdx.x * 256 + threadIdx.x;
    const int t  = threadIdx.x;

    __shared__ float redc[2][128];
    __shared__ float cw[128];
    const int jj = t & 127, half = t >> 7;
    const float* __restrict__ cpb = colw_part + (size_t)b * 512 * SB + j0 + jj;
    float s = 0.f;
    #pragma unroll 8
    for (int ic = half * 256; ic < half * 256 + 256; ++ic)
        s += cpb[(size_t)ic * SB];
    redc[half][jj] = s;
    __syncthreads();
    if (t < 128) cw[t] = redc[0][t] + redc[1][t];
    __syncthreads();

    float acc = 0.f;
    #pragma unroll 8
    for (int x = 0; x < 128; ++x)
        acc = fmaf(cw[x], lstm[(size_t)(b * SB + j0 + x) * HH + h], acc);
    atomicAdd(&ctx[b * HH + h], acc);
}

extern "C" void kernel_launch(void* const* d_in, const int* in_sizes, int n_in,
                              void* d_out, int out_size, void* d_ws, size_t ws_size,
                              hipStream_t stream)
{
    const float* lstm = (const float*)d_in[0];   // (B,S,H)
    const float* w    = (const float*)d_in[1];   // (H,A)
    const float* u    = (const float*)d_in[2];   // (H,A)
    const float* v    = (const float*)d_in[3];   // (A,)

    float* out  = (float*)d_out;
    float* ctx  = out;                     // (B,H)   = 1024 floats
    float* attn = out + BATCH * HH;        // (B,S,S) = 2M floats

    float* part0     = (float*)d_ws;                          // 2 MB
    float* part1     = part0 + (size_t)2048 * 256;            // 2 MB
    float* P         = part1 + (size_t)2048 * 256;            // 1 MB
    float* Qt        = P     + (size_t)BATCH * SB * AA;       // 1 MB (tiled)
    float* colw_part = Qt    + (size_t)BATCH * SB * AA;       // 4 MB
    float* vsum      = colw_part + (size_t)BATCH * 512 * SB;  // 4 B

    k1_gemm<<<dim3(32, 8, 2), 256, 0, stream>>>(lstm, w, u, v, part0, part1, ctx, vsum);
    k1b_combine_exp<<<dim3(512), 256, 0, stream>>>(part0, part1, P, Qt);
    k2a_fused<<<dim3(512, BATCH), 256, 0, stream>>>(P, Qt, v, vsum, attn, colw_part);
    k4_context<<<dim3(2, 8, BATCH), 256, 0, stream>>>(lstm, colw_part, ctx);
}

// Round 11
// 66.530 us; speedup vs baseline: 2.0261x; 1.1405x over previous
//
#include <hip/hip_runtime.h>

#define HH   512
#define AA   128
#define SB   1024
#define BATCH 2

__device__ __forceinline__ float fast_rcp(float x) { return __builtin_amdgcn_rcpf(x); }
__device__ __forceinline__ float fast_ex2(float x) { return __builtin_amdgcn_exp2f(x); }

// Sum over a quad: v0/d0+v1/d1+v2/d2+v3/d3 = (na*p23 + nb*p01) / (p01*p23).
// 11 VALU + 1 rcp per 4 elements.
__device__ __forceinline__ void quad_acc(const float4 p, const float4 q4,
                                         const float4 vv, float& acc)
{
    const float d0 = fmaf(p.x, q4.x, 1.0f);
    const float d1 = fmaf(p.y, q4.y, 1.0f);
    const float d2 = fmaf(p.z, q4.z, 1.0f);
    const float d3 = fmaf(p.w, q4.w, 1.0f);
    const float p01 = d0 * d1, p23 = d2 * d3;
    const float na = fmaf(vv.x, d1, vv.y * d0);
    const float nb = fmaf(vv.z, d3, vv.w * d2);
    const float N  = fmaf(na, p23, nb * p01);
    acc = fmaf(N, fast_rcp(p01 * p23), acc);
}

// K1: partial GEMM C = lstm(2048x512) @ [w|u](512x256), K split 4 ways.
// A-BROADCAST design: A tile [16m][128k] staged ONCE in LDS, read as
// wave-uniform b128 broadcasts (zero LDS bandwidth); B read per-lane as
// coalesced float4 from global (256KB, L1/L2-resident, 4-way wave reuse).
// Thread tile 4m x 4n -> 1 B/fma LDS-side => FMA-bound. grid (128, 4).
// Block (0,0) zeroes ctx + computes vsum.
__global__ __launch_bounds__(256) void k1_gemm(const float* __restrict__ lstm,
                                               const float* __restrict__ w,
                                               const float* __restrict__ u,
                                               const float* __restrict__ v,
                                               float* __restrict__ parts,
                                               float* __restrict__ ctx,
                                               float* __restrict__ vsum)
{
    __shared__ float As[16 * 128];                 // [m][k], 8KB
    const int t  = threadIdx.x;
    const int m0 = blockIdx.x * 16;
    const int kz = blockIdx.y * 128;

    if (blockIdx.x == 0 && blockIdx.y == 0) {
        #pragma unroll
        for (int r = 0; r < 4; ++r) ctx[r * 256 + t] = 0.f;
        if (t < 64) {
            float s = v[t] + v[t + 64];
            #pragma unroll
            for (int off = 32; off > 0; off >>= 1) s += __shfl_xor(s, off);
            if (t == 0) vsum[0] = s;
        }
    }

    {   // stage A once: 2048 floats, 2 float4/thread, coalesced
        const int sm = t >> 4;                     // 0..15
        const int sq = (t & 15) * 8;               // 0..120
        const float* src = &lstm[(size_t)(m0 + sm) * HH + kz + sq];
        *(float4*)&As[sm * 128 + sq]     = *(const float4*)&src[0];
        *(float4*)&As[sm * 128 + sq + 4] = *(const float4*)&src[4];
    }
    __syncthreads();

    const int cc = (t & 63) * 4;                   // global col group 0..252
    const float* __restrict__ Bp = (cc < AA) ? (w + cc) : (u + cc - AA);
    const int mh = t >> 6;                         // wave-uniform m-group

    float acc[4][4];
    #pragma unroll
    for (int mm = 0; mm < 4; ++mm)
        #pragma unroll
        for (int nn = 0; nn < 4; ++nn) acc[mm][nn] = 0.f;

    #pragma unroll 4
    for (int kq = 0; kq < 32; ++kq) {
        float4 bq[4];
        #pragma unroll
        for (int kk = 0; kk < 4; ++kk)
            bq[kk] = *(const float4*)&Bp[(size_t)(kz + kq * 4 + kk) * AA];  // coalesced
        #pragma unroll
        for (int mm = 0; mm < 4; ++mm) {
            const float4 am = *(const float4*)&As[(mh * 4 + mm) * 128 + kq * 4]; // broadcast
            #pragma unroll
            for (int kk = 0; kk < 4; ++kk) {
                const float a = (kk == 0) ? am.x : (kk == 1) ? am.y : (kk == 2) ? am.z : am.w;
                const float4 bb = bq[kk];
                acc[mm][0] = fmaf(a, bb.x, acc[mm][0]);
                acc[mm][1] = fmaf(a, bb.y, acc[mm][1]);
                acc[mm][2] = fmaf(a, bb.z, acc[mm][2]);
                acc[mm][3] = fmaf(a, bb.w, acc[mm][3]);
            }
        }
    }

    float* __restrict__ part = parts + (size_t)blockIdx.y * (2048 * 256);
    #pragma unroll
    for (int mm = 0; mm < 4; ++mm) {
        float4 s; s.x = acc[mm][0]; s.y = acc[mm][1]; s.z = acc[mm][2]; s.w = acc[mm][3];
        *(float4*)&part[(size_t)(m0 + mh * 4 + mm) * 256 + cc] = s;
    }
}

// K1b: o = exp2(KK * sum of 4 partials); P row-major [m][a]; Q tiled Qt[b][aq][j]
// (float4 = a-quad of column j -> k2a loads are lane-coalesced).
// Blocks 0..31 also zero colw_sub. grid (512), 256 threads.
__global__ __launch_bounds__(256) void k1b_combine_exp(const float* __restrict__ parts,
                                                       float* __restrict__ P,
                                                       float* __restrict__ Qt,
                                                       float* __restrict__ colw_sub)
{
    const float KK = 2.8853900817779268f;            // 2 * log2(e)
    const int t   = threadIdx.x;
    const int idx = blockIdx.x * 256 + t;            // 0..131071 float4s
    if (blockIdx.x < 32) {                           // zero colw_sub (32K floats)
        float4 z4; z4.x = z4.y = z4.z = z4.w = 0.f;
        ((float4*)colw_sub)[blockIdx.x * 256 + t] = z4;
    }
    const float4 c0 = ((const float4*)parts)[idx];
    const float4 c1 = ((const float4*)parts)[idx + 131072];
    const float4 c2 = ((const float4*)parts)[idx + 262144];
    const float4 c3 = ((const float4*)parts)[idx + 393216];
    float4 o;
    o.x = fast_ex2(KK * ((c0.x + c1.x) + (c2.x + c3.x)));
    o.y = fast_ex2(KK * ((c0.y + c1.y) + (c2.y + c3.y)));
    o.z = fast_ex2(KK * ((c0.z + c1.z) + (c2.z + c3.z)));
    o.w = fast_ex2(KK * ((c0.w + c1.w) + (c2.w + c3.w)));
    const int m  = idx >> 6;                          // global row 0..2047
    const int qd = idx & 63;                          // a-quad within 256-col row
    if (qd < 32) {
        *(float4*)&P[(size_t)m * AA + qd * 4] = o;
    } else {
        const int aq = qd - 32;                       // 0..31
        const int b  = m >> 10;
        const int j  = m & (SB - 1);
        ((float4*)Qt)[((size_t)(b * 32 + aq)) * SB + j] = o;
    }
}

// K2a: fused e-score + softmax + column-slice sums.
// Block = 4 i-rows x all 1024 j (512 threads, J=2: j = t, t+512). grid (256, 2).
// P rows + v in LDS (broadcast b128, zero-BW); Q from tiled Qt -> coalesced b128.
// E in regs, row-sums block-reduced, attn written ONCE normalized, column sums
// atomically added into one of 16 slices (16-way contention).
__global__ __launch_bounds__(512) void k2a_fused(const float* __restrict__ P,
                                                 const float* __restrict__ Qt,
                                                 const float* __restrict__ v,
                                                 const float* __restrict__ vsum,
                                                 float* __restrict__ attn,
                                                 float* __restrict__ colw_sub)
{
    __shared__ float Pl[4 * AA];
    __shared__ float vl[AA];
    __shared__ float red[4][8];
    const int b  = blockIdx.y;
    const int i0 = blockIdx.x * 4;
    const int t  = threadIdx.x;

    if (t < 128)      ((float4*)Pl)[t] = ((const float4*)&P[((size_t)b * SB + i0) * AA])[t];
    else if (t < 160) ((float4*)vl)[t - 128] = ((const float4*)v)[t - 128];
    __syncthreads();

    const float4* __restrict__ Q4 = (const float4*)Qt + (size_t)b * 32 * SB;
    const int j0 = t, j1 = t + 512;

    float acc[4][2];
    #pragma unroll
    for (int i = 0; i < 4; ++i) { acc[i][0] = 0.f; acc[i][1] = 0.f; }

    #pragma unroll 2
    for (int aq = 0; aq < 32; ++aq) {
        const float4 q0 = Q4[(size_t)aq * SB + j0];
        const float4 q1 = Q4[(size_t)aq * SB + j1];
        const float4 vv = *(const float4*)&vl[aq * 4];           // LDS broadcast
        #pragma unroll
        for (int i = 0; i < 4; ++i) {
            const float4 p = *(const float4*)&Pl[i * AA + aq * 4]; // LDS broadcast
            quad_acc(p, q0, vv, acc[i][0]);
            quad_acc(p, q1, vv, acc[i][1]);
        }
    }

    // e = Vsum - 2*acc; E = exp2(L2E*Vsum - 2*L2E*acc). |e| <= ~9 -> no max pass.
    const float L2E  = 1.4426950408889634f;
    const float base = vsum[0] * L2E;                 // one uniform s_load
    float E[4][2];
    #pragma unroll
    for (int i = 0; i < 4; ++i) {
        E[i][0] = fast_ex2(fmaf(acc[i][0], -2.0f * L2E, base));
        E[i][1] = fast_ex2(fmaf(acc[i][1], -2.0f * L2E, base));
    }

    const int lane = t & 63, wv = t >> 6;
    #pragma unroll
    for (int i = 0; i < 4; ++i) {
        float s = E[i][0] + E[i][1];
        #pragma unroll
        for (int off = 32; off > 0; off >>= 1) s += __shfl_xor(s, off);
        if (lane == 0) red[i][wv] = s;
    }
    __syncthreads();

    float* __restrict__ arow = &attn[((size_t)(b * SB + i0)) * SB];
    float* __restrict__ cs   = &colw_sub[((size_t)(b * 16 + (blockIdx.x & 15))) * SB];
    float csum0 = 0.f, csum1 = 0.f;
    #pragma unroll
    for (int i = 0; i < 4; ++i) {
        const float4* rr = (const float4*)red[i];
        const float4 r0 = rr[0], r1 = rr[1];
        const float rs = ((r0.x + r0.y) + (r0.z + r0.w)) + ((r1.x + r1.y) + (r1.z + r1.w));
        const float inv = fast_rcp(rs);
        const float a0 = E[i][0] * inv;
        const float a1 = E[i][1] * inv;
        arow[(size_t)i * SB + j0] = a0;
        arow[(size_t)i * SB + j1] = a1;
        csum0 += a0;
        csum1 += a1;
    }
    atomicAdd(&cs[j0], csum0);
    atomicAdd(&cs[j1], csum1);
}

// K4: cw[j] = sum of 16 colw slices; ctx[b,h] += sum_j cw[j]*lstm[b,j,h].
// grid (2 hc, 8 jc, 2 b) = 32 blocks, 256 threads.
__global__ __launch_bounds__(256) void k4_context(const float* __restrict__ lstm,
                                                  const float* __restrict__ colw_sub,
                                                  float* __restrict__ ctx)
{
    const int b  = blockIdx.z;
    const int j0 = blockIdx.y * 128;
    const int h  = blockIdx.x * 256 + threadIdx.x;
    const int t  = threadIdx.x;

    __shared__ float cw[128];
    if (t < 128) {
        float s = 0.f;
        #pragma unroll
        for (int sl = 0; sl < 16; ++sl)
            s += colw_sub[(size_t)(b * 16 + sl) * SB + j0 + t];
        cw[t] = s;
    }
    __syncthreads();

    float acc = 0.f;
    #pragma unroll 8
    for (int jj = 0; jj < 128; ++jj)
        acc = fmaf(cw[jj], lstm[(size_t)(b * SB + j0 + jj) * HH + h], acc);
    atomicAdd(&ctx[b * HH + h], acc);
}

extern "C" void kernel_launch(void* const* d_in, const int* in_sizes, int n_in,
                              void* d_out, int out_size, void* d_ws, size_t ws_size,
                              hipStream_t stream)
{
    const float* lstm = (const float*)d_in[0];   // (B,S,H)
    const float* w    = (const float*)d_in[1];   // (H,A)
    const float* u    = (const float*)d_in[2];   // (H,A)
    const float* v    = (const float*)d_in[3];   // (A,)

    float* out  = (float*)d_out;
    float* ctx  = out;                     // (B,H)   = 1024 floats
    float* attn = out + BATCH * HH;        // (B,S,S) = 2M floats

    float* parts    = (float*)d_ws;                           // 4 x 2 MB
    float* P        = parts + (size_t)4 * 2048 * 256;         // 1 MB
    float* Qt       = P     + (size_t)BATCH * SB * AA;        // 1 MB (tiled)
    float* colw_sub = Qt    + (size_t)BATCH * SB * AA;        // 2*16*1024 = 128 KB
    float* vsum     = colw_sub + (size_t)BATCH * 16 * SB;     // 4 B

    k1_gemm<<<dim3(128, 4), 256, 0, stream>>>(lstm, w, u, v, parts, ctx, vsum);
    k1b_combine_exp<<<dim3(512), 256, 0, stream>>>(parts, P, Qt, colw_sub);
    k2a_fused<<<dim3(256, BATCH), 512, 0, stream>>>(P, Qt, v, vsum, attn, colw_sub);
    k4_context<<<dim3(2, 8, BATCH), 256, 0, stream>>>(lstm, colw_sub, ctx);
}